// Round 8
// baseline (61.035 us; speedup 1.0000x reference)
//
#include <hip/hip_runtime.h>
#include <math.h>

// Problem constants
#define NB 2
#define HIMG 96
#define HO 65
#define NCROPS (NB*HO*HO)   // 8450

// pool1: [cls3=(img,o1,o2)][16ch][46][46]
#define P1_PLANE (46*46)          // 2116
#define P1_SIZE (8*16*P1_PLANE)   // 270848
// pool2: [cls5=(img,o1,o2,p1,p2)][32ch][22][22] f32
#define P2_PLANE (22*22)          // 484
#define P2_SIZE (32*32*P2_PLANE)  // 495616
// wBt: fragment-blocked padded weights [nf 8][ki 48][lane 64][8] bf16
#define WBT_SIZE (8*48*64*8)      // 196608

typedef __attribute__((ext_vector_type(8))) short bf16x8;
typedef __attribute__((ext_vector_type(4))) float f32x4;
typedef __attribute__((ext_vector_type(4), aligned(4))) float f32x4u;  // 4B-aligned vec load
typedef __attribute__((ext_vector_type(4))) unsigned int u32x4;

__device__ __forceinline__ unsigned int f2bf(float x) {
    unsigned int u = __builtin_bit_cast(unsigned int, x);
    return (u + 0x7fffu + ((u >> 16) & 1u)) >> 16;
}
__device__ __forceinline__ unsigned int cvtpk(float lo, float hi) {
    unsigned int r;
    asm("v_cvt_pk_bf16_f32 %0, %1, %2" : "=v"(r) : "v"(lo), "v"(hi));
    return r;
}

// Merged front kernel:
//   blocks [0,529)    : conv1(5x5,1->16)+ReLU+2x2 maxpool at parity -> pool1
//   blocks [529,625)  : build wBt (fragment-blocked, nn'-padded bf16 fc1 weights)
//   blocks [625,697)  : zero heatmap
//   blocks [697,1181) : zero pool2 (float4, 484 blocks exact)
__global__ void k_front(const float* __restrict__ x, const float* __restrict__ w1,
                        const float* __restrict__ b1, float* __restrict__ pool1,
                        const float* __restrict__ fc1_w, unsigned short* __restrict__ wBt,
                        float* __restrict__ pool2, float* __restrict__ out) {
    int b = blockIdx.x, tid = threadIdx.x;
    if (b >= 529) {
        if (b < 625) {
            int g = (b - 529) * 256 + tid;        // < 24576, one 16B chunk each
            int l = g & 63;
            int t2 = g >> 6;                      // < 384
            int ki = t2 % 48, nf = t2 / 48;
            int n  = nf * 16 + (l & 15);
            int lg = l >> 4;
            int ch = (ki & 7) * 4 + lg;           // matches k_fc: ch=((kk*4)&31)+lg
            int mm = (ki / 24) * 3 + ((ki >> 3) % 3);  // matches k_fc: mm=kh*3+(kk>>3)
            const float* src = fc1_w + n * 1152 + ch * 36 + mm * 6;
            uint4 v;
            v.x = f2bf(src[0]) | (f2bf(src[1]) << 16);
            v.y = f2bf(src[2]) | (f2bf(src[3]) << 16);
            v.z = f2bf(src[4]) | (f2bf(src[5]) << 16);
            v.w = 0;                              // nn' = 6,7 zero-padded
            ((uint4*)wBt)[g] = v;
        } else if (b < 697) {
            out[(b - 625) * 256 + tid] = 0.f;
        } else {
            float4 z; z.x = 0.f; z.y = 0.f; z.z = 0.f; z.w = 0.f;
            ((float4*)pool2)[(b - 697) * 256 + tid] = z;
        }
        return;
    }
    int idx = b * 256 + tid;                          // < 135424
    int pg = idx % 23;
    int t  = idx / 23;
    int py = t % 46;  t /= 46;
    int ch = t % 16;  t /= 16;                        // t = cls3
    int o2 = t & 1, o1 = (t >> 1) & 1, img = t >> 2;
    const float* xim = x + img * (HIMG * HIMG);

    int rbase = 2 * py + o1;
    int cbase = 4 * pg + o2;
    float a[6][8];
    #pragma unroll
    for (int i = 0; i < 6; ++i) {
        int r = rbase + i; if (r > 95) r = 95;
        const float* rp = xim + r * 96;
        #pragma unroll
        for (int j = 0; j < 8; ++j) {
            int c = cbase + j; if (c > 95) c = 95;
            a[i][j] = rp[c];
        }
    }
    const float* wc = w1 + ch * 25;
    float w[25];
    #pragma unroll
    for (int u = 0; u < 25; ++u) w[u] = wc[u];
    float bias = b1[ch];

    float out0 = 0.f, out1 = 0.f;   // relu'd values >= 0
    #pragma unroll
    for (int dy = 0; dy < 2; ++dy)
        #pragma unroll
        for (int dx = 0; dx < 2; ++dx) {
            float s0 = bias, s1 = bias;
            #pragma unroll
            for (int ky = 0; ky < 5; ++ky)
                #pragma unroll
                for (int kx = 0; kx < 5; ++kx) {
                    float wv = w[ky * 5 + kx];
                    s0 += a[dy + ky][dx + kx] * wv;
                    s1 += a[dy + ky][2 + dx + kx] * wv;
                }
            out0 = fmaxf(out0, s0);
            out1 = fmaxf(out1, s1);
        }
    int base = ((t * 16 + ch) * 46 + py) * 46 + 2 * pg;
    float2 v; v.x = out0; v.y = out1;
    *(float2*)&pool1[base] = v;
}

// conv2(3x3,16->32)+ReLU fused with pool2 scatter: each thread computes 4
// conv2 values along x and atomicMax's them into the 4 parity-class pool2
// cells each value feeds. Values >= 0 so float bits are uint-monotonic.
__global__ void k_conv2p(const float* __restrict__ pool1, const float* __restrict__ w2,
                         const float* __restrict__ b2, float* __restrict__ pool2) {
    int idx = blockIdx.x * 256 + threadIdx.x;     // < 123904
    int og = idx % 11;
    int t  = idx / 11;
    int oy = t % 44;  t /= 44;
    int oc = t % 32;  t /= 32;                    // t = cls3
    int ox0 = og * 4;
    const float* p1 = pool1 + t * 16 * P1_PLANE + oy * 46 + ox0;
    const float* ww = w2 + oc * 144;
    float b = b2[oc];
    float s0 = b, s1 = b, s2 = b, s3 = b;
    for (int ic = 0; ic < 16; ++ic) {
        const float* pp = p1 + ic * P1_PLANE;
        const float* wk = ww + ic * 9;
        #pragma unroll
        for (int ky = 0; ky < 3; ++ky) {
            const float* r = pp + ky * 46;
            float w0 = wk[ky * 3], w1v = wk[ky * 3 + 1], w2v = wk[ky * 3 + 2];
            float a0 = r[0], a1 = r[1], a2 = r[2], a3 = r[3], a4 = r[4], a5 = r[5];
            s0 += a0 * w0 + a1 * w1v + a2 * w2v;
            s1 += a1 * w0 + a2 * w1v + a3 * w2v;
            s2 += a2 * w0 + a3 * w1v + a4 * w2v;
            s3 += a3 * w0 + a4 * w1v + a5 * w2v;
        }
    }
    float v0 = fmaxf(s0, 0.f), v1 = fmaxf(s1, 0.f);
    float v2 = fmaxf(s2, 0.f), v3 = fmaxf(s3, 0.f);

    // Scatter: value at col c feeds (p2, ex=(c-p2)>>1); merge same-target pairs.
    unsigned vb01 = __float_as_uint(fmaxf(v0, v1));
    unsigned vb23 = __float_as_uint(fmaxf(v2, v3));
    unsigned vb12 = __float_as_uint(fmaxf(v1, v2));
    unsigned vb0  = __float_as_uint(v0);
    unsigned vb3  = __float_as_uint(v3);
    unsigned* pu = (unsigned*)pool2;
    int ex0 = 2 * og;
    #pragma unroll
    for (int p1v = 0; p1v < 2; ++p1v) {
        int eyq = oy - p1v;
        if (eyq < 0) continue;
        int ey = eyq >> 1;                        // oy<=43 -> ey<=21
        unsigned b0a = ((unsigned)((t * 4 + p1v * 2 + 0) * 32 + oc)) * 484 + ey * 22 + ex0;
        unsigned b1a = ((unsigned)((t * 4 + p1v * 2 + 1) * 32 + oc)) * 484 + ey * 22 + ex0;
        atomicMax(&pu[b0a],     vb01);
        atomicMax(&pu[b0a + 1], vb23);
        if (og > 0) atomicMax(&pu[b1a - 1], vb0);
        atomicMax(&pu[b1a],     vb12);
        atomicMax(&pu[b1a + 1], vb3);
    }
}

// FC GEMM with contiguous-M ordering: m = cls5*289 + c*17 + d  (d fastest).
// A-fragment loads are near-contiguous plane-row reads (no lane scatter);
// B streams from fragment-blocked wBt (1KB contiguous per instruction).
// K' = 1536 (nn' padded 6->8, zero weights). 8 waves = 4 N-slices x 2 K-halves;
// halves reduced via LDS; fused bias/ReLU/FC2/sigmoid/scatter.
__global__ __launch_bounds__(512, 4) void k_fc(const float* __restrict__ pool2,
                                               const unsigned short* __restrict__ wBt,
                                               const float* __restrict__ fc1_b,
                                               const float* __restrict__ fc2_w,
                                               const float* __restrict__ fc2_b,
                                               float* __restrict__ out) {
    __shared__ __align__(16) float shH[32][132];

    int tid  = threadIdx.x;
    int lane = tid & 63, wid = tid >> 6;
    int nsl = wid & 3, kh = wid >> 2;       // N-slice, K-half
    int lm = lane & 15, lg = lane >> 4;
    int m0 = blockIdx.x * 32;

    const float* aF0;
    const float* aF1;
    {
        int m = m0 + lm;
        int cls5 = m / 289, r = m - cls5 * 289;
        int c = r / 17, d = r - c * 17;
        aF0 = pool2 + cls5 * (32 * P2_PLANE) + c * 22 + d + lg * P2_PLANE + kh * 66;
        m += 16;
        cls5 = m / 289; r = m - cls5 * 289;
        c = r / 17; d = r - c * 17;
        aF1 = pool2 + cls5 * (32 * P2_PLANE) + c * 22 + d + lg * P2_PLANE + kh * 66;
    }
    const unsigned short* bp0 = wBt + (((nsl * 2) * 48 + kh * 24) * 64 + lane) * 8;
    const unsigned short* bp1 = bp0 + 48 * 64 * 8;

    f32x4 acc00 = {0.f,0.f,0.f,0.f}, acc01 = {0.f,0.f,0.f,0.f};
    f32x4 acc10 = {0.f,0.f,0.f,0.f}, acc11 = {0.f,0.f,0.f,0.f};

    #pragma unroll 4
    for (int kk = 0; kk < 24; ++kk) {
        int S = (kk & 7) * (4 * P2_PLANE) + (kk >> 3) * 22;   // (ch-lg)*484 + (mm-kh*3)*22
        f32x4u lo0 = *(const f32x4u*)(aF0 + S);
        f32x4u hi0 = *(const f32x4u*)(aF0 + S + 4);
        f32x4u lo1 = *(const f32x4u*)(aF1 + S);
        f32x4u hi1 = *(const f32x4u*)(aF1 + S + 4);
        bf16x8 b0 = *(const bf16x8*)(bp0 + kk * 512);
        bf16x8 b1 = *(const bf16x8*)(bp1 + kk * 512);
        u32x4 u0 = { cvtpk(lo0.x, lo0.y), cvtpk(lo0.z, lo0.w),
                     cvtpk(hi0.x, hi0.y), cvtpk(hi0.z, hi0.w) };
        u32x4 u1 = { cvtpk(lo1.x, lo1.y), cvtpk(lo1.z, lo1.w),
                     cvtpk(hi1.x, hi1.y), cvtpk(hi1.z, hi1.w) };
        bf16x8 a0 = __builtin_bit_cast(bf16x8, u0);
        bf16x8 a1 = __builtin_bit_cast(bf16x8, u1);
        acc00 = __builtin_amdgcn_mfma_f32_16x16x32_bf16(a0, b0, acc00, 0, 0, 0);
        acc01 = __builtin_amdgcn_mfma_f32_16x16x32_bf16(a0, b1, acc01, 0, 0, 0);
        acc10 = __builtin_amdgcn_mfma_f32_16x16x32_bf16(a1, b0, acc10, 0, 0, 0);
        acc11 = __builtin_amdgcn_mfma_f32_16x16x32_bf16(a1, b1, acc11, 0, 0, 0);
    }

    int col = nsl * 32 + lm;
    if (kh == 0) {
        #pragma unroll
        for (int r = 0; r < 4; ++r) {
            shH[lg * 4 + r][col]           = acc00[r];
            shH[lg * 4 + r][col + 16]      = acc01[r];
            shH[16 + lg * 4 + r][col]      = acc10[r];
            shH[16 + lg * 4 + r][col + 16] = acc11[r];
        }
    }
    __syncthreads();
    if (kh == 1) {
        #pragma unroll
        for (int r = 0; r < 4; ++r) {
            shH[lg * 4 + r][col]           += acc00[r];
            shH[lg * 4 + r][col + 16]      += acc01[r];
            shH[16 + lg * 4 + r][col]      += acc10[r];
            shH[16 + lg * 4 + r][col + 16] += acc11[r];
        }
    }
    __syncthreads();

    // FC2: 512 thr = 32 rows x 16 parts, 8 elems each; reduce within 16 lanes.
    int row = tid >> 4, part = tid & 15;
    const float* hh = shH[row];
    float s = 0.f;
    #pragma unroll
    for (int u = 0; u < 8; ++u)
        s += fmaxf(hh[part * 8 + u] + fc1_b[part * 8 + u], 0.f) * fc2_w[part * 8 + u];
    s += __shfl_down(s, 8, 16);
    s += __shfl_down(s, 4, 16);
    s += __shfl_down(s, 2, 16);
    s += __shfl_down(s, 1, 16);
    if (part == 0) {
        int m = m0 + row;                   // < 9248 always
        int cls5 = m / 289, r2 = m - cls5 * 289;
        int c = r2 / 17, d = r2 - c * 17;
        int img = cls5 >> 4, o1 = (cls5 >> 3) & 1, o2 = (cls5 >> 2) & 1;
        int p1 = (cls5 >> 1) & 1, p2 = cls5 & 1;
        int i = 4 * c + 2 * p1 + o1;
        int j = 4 * d + 2 * p2 + o2;
        if (i <= 64 && j <= 64) {
            float q = 1.f / (1.f + expf(-(s + fc2_b[0])));
            out[img * (HIMG * HIMG) + (16 + i) * HIMG + (16 + j)] = q;
        }
    }
}

extern "C" void kernel_launch(void* const* d_in, const int* in_sizes, int n_in,
                              void* d_out, int out_size, void* d_ws, size_t ws_size,
                              hipStream_t stream) {
    const float* x     = (const float*)d_in[0];
    const float* w1    = (const float*)d_in[1];
    const float* b1    = (const float*)d_in[2];
    const float* w2    = (const float*)d_in[3];
    const float* b2    = (const float*)d_in[4];
    const float* fc1_w = (const float*)d_in[5];
    const float* fc1_b = (const float*)d_in[6];
    const float* fc2_w = (const float*)d_in[7];
    const float* fc2_b = (const float*)d_in[8];
    float* out = (float*)d_out;

    float* ws    = (float*)d_ws;
    float* pool1 = ws;                         // 270848 f32
    float* pool2 = pool1 + P1_SIZE;            // 495616 f32
    unsigned short* wBt = (unsigned short*)(pool2 + P2_SIZE);  // 196608 bf16

    k_front<<<1181, 256, 0, stream>>>(x, w1, b1, pool1, fc1_w, wBt, pool2, out);
    k_conv2p<<<484, 256, 0, stream>>>(pool1, w2, b2, pool2);
    k_fc<<<289, 512, 0, stream>>>(pool2, wBt, fc1_b, fc2_w, fc2_b, out);
}

// Round 9
// 45.876 us; speedup vs baseline: 1.3304x; 1.3304x over previous
//
#include <hip/hip_runtime.h>
#include <math.h>

// Problem constants
#define NB 2
#define HIMG 96
#define HO 65
#define NCROPS (NB*HO*HO)   // 8450

// pool1: [cls3=(img,o1,o2)][16ch][46][46]
#define P1_PLANE (46*46)          // 2116
#define P1_SIZE (8*16*P1_PLANE)   // 270848
// pool2: [cls5=(img,o1,o2,p1,p2)][32ch][22][22] f32
#define P2_PLANE (22*22)          // 484
#define P2_SIZE (32*32*P2_PLANE)  // 495616
// wBt: fragment-blocked padded weights [nf 8][kb 192][lm 16][8] bf16
//   kb = mm*32 + ch  (ch 0..31, mm 0..5), k' = kb*8 + nn', nn'6,7 zero-padded
#define WBT_SIZE (8*192*16*8)     // 196608

typedef __attribute__((ext_vector_type(8))) short bf16x8;
typedef __attribute__((ext_vector_type(4))) float f32x4;
typedef __attribute__((ext_vector_type(4), aligned(4))) float f32x4u;  // 4B-aligned vec load
typedef __attribute__((ext_vector_type(4))) unsigned int u32x4;

__device__ __forceinline__ unsigned int f2bf(float x) {
    unsigned int u = __builtin_bit_cast(unsigned int, x);
    return (u + 0x7fffu + ((u >> 16) & 1u)) >> 16;
}
__device__ __forceinline__ unsigned int cvtpk(float lo, float hi) {
    unsigned int r;
    asm("v_cvt_pk_bf16_f32 %0, %1, %2" : "=v"(r) : "v"(lo), "v"(hi));
    return r;
}

// Merged front kernel:
//   blocks [0,529)   : conv1(5x5,1->16)+ReLU+2x2 maxpool at parity -> pool1
//   blocks [529,625) : build wBt
//   blocks [625,697) : zero heatmap
__global__ void k_front(const float* __restrict__ x, const float* __restrict__ w1,
                        const float* __restrict__ b1, float* __restrict__ pool1,
                        const float* __restrict__ fc1_w, unsigned short* __restrict__ wBt,
                        float* __restrict__ out) {
    int b = blockIdx.x, tid = threadIdx.x;
    if (b >= 529) {
        if (b < 625) {
            int g = (b - 529) * 256 + tid;        // < 24576, one 16B chunk each
            int lm = g & 15;
            int kb = (g >> 4) % 192;
            int nf = g / 3072;
            int n  = nf * 16 + lm;
            int ch = kb & 31, mm = kb >> 5;
            const float* src = fc1_w + n * 1152 + ch * 36 + mm * 6;
            uint4 v;
            v.x = f2bf(src[0]) | (f2bf(src[1]) << 16);
            v.y = f2bf(src[2]) | (f2bf(src[3]) << 16);
            v.z = f2bf(src[4]) | (f2bf(src[5]) << 16);
            v.w = 0;                              // nn' = 6,7 zero-padded
            ((uint4*)wBt)[g] = v;
        } else {
            out[(b - 625) * 256 + tid] = 0.f;
        }
        return;
    }
    int idx = b * 256 + tid;                          // < 135424
    int pg = idx % 23;
    int t  = idx / 23;
    int py = t % 46;  t /= 46;
    int ch = t % 16;  t /= 16;                        // t = cls3
    int o2 = t & 1, o1 = (t >> 1) & 1, img = t >> 2;
    const float* xim = x + img * (HIMG * HIMG);

    int rbase = 2 * py + o1;
    int cbase = 4 * pg + o2;
    float a[6][8];
    #pragma unroll
    for (int i = 0; i < 6; ++i) {
        int r = rbase + i; if (r > 95) r = 95;
        const float* rp = xim + r * 96;
        #pragma unroll
        for (int j = 0; j < 8; ++j) {
            int c = cbase + j; if (c > 95) c = 95;
            a[i][j] = rp[c];
        }
    }
    const float* wc = w1 + ch * 25;
    float w[25];
    #pragma unroll
    for (int u = 0; u < 25; ++u) w[u] = wc[u];
    float bias = b1[ch];

    float out0 = 0.f, out1 = 0.f;   // relu'd values >= 0
    #pragma unroll
    for (int dy = 0; dy < 2; ++dy)
        #pragma unroll
        for (int dx = 0; dx < 2; ++dx) {
            float s0 = bias, s1 = bias;
            #pragma unroll
            for (int ky = 0; ky < 5; ++ky)
                #pragma unroll
                for (int kx = 0; kx < 5; ++kx) {
                    float wv = w[ky * 5 + kx];
                    s0 += a[dy + ky][dx + kx] * wv;
                    s1 += a[dy + ky][2 + dx + kx] * wv;
                }
            out0 = fmaxf(out0, s0);
            out1 = fmaxf(out1, s1);
        }
    int base = ((t * 16 + ch) * 46 + py) * 46 + 2 * pg;
    float2 v; v.x = out0; v.y = out1;
    *(float2*)&pool1[base] = v;
}

// Fused conv2(3x3,16->32)+ReLU+pool2: block = (cls3, oc, row-half h).
// Computes a 23-row conv2 strip into LDS, then pools all 4 (p1,p2) classes.
// No conv2 global buffer, no atomics, pool2 written exactly once.
__global__ __launch_bounds__(256) void k_convpool(const float* __restrict__ pool1,
                                                  const float* __restrict__ w2,
                                                  const float* __restrict__ b2,
                                                  float* __restrict__ pool2) {
    __shared__ float sc[23][45];
    int b = blockIdx.x;                     // < 512
    int h = b & 1, oc = (b >> 1) & 31, cls3 = b >> 6;
    int tid = threadIdx.x;
    const float* p1base = pool1 + cls3 * 16 * P1_PLANE;
    const float* ww = w2 + oc * 144;        // block-uniform -> scalarized
    float bias = b2[oc];

    // conv phase: quad q = tid covers (rl = q/11, ox0 = (q%11)*4); 253 quads
    if (tid < 253) {
        int rl = tid / 11, og = tid - rl * 11;
        int oy = h * 22 + rl;
        if (oy < 44) {
            int ox0 = og * 4;
            const float* p1 = p1base + oy * 46 + ox0;
            float s0 = bias, s1 = bias, s2 = bias, s3 = bias;
            for (int ic = 0; ic < 16; ++ic) {
                const float* pp = p1 + ic * P1_PLANE;
                const float* wk = ww + ic * 9;
                #pragma unroll
                for (int ky = 0; ky < 3; ++ky) {
                    const float* r = pp + ky * 46;
                    float w0 = wk[ky * 3], w1v = wk[ky * 3 + 1], w2v = wk[ky * 3 + 2];
                    float a0 = r[0], a1 = r[1], a2 = r[2], a3 = r[3], a4 = r[4], a5 = r[5];
                    s0 += a0 * w0 + a1 * w1v + a2 * w2v;
                    s1 += a1 * w0 + a2 * w1v + a3 * w2v;
                    s2 += a2 * w0 + a3 * w1v + a4 * w2v;
                    s3 += a3 * w0 + a4 * w1v + a5 * w2v;
                }
            }
            sc[rl][ox0]     = fmaxf(s0, 0.f);
            sc[rl][ox0 + 1] = fmaxf(s1, 0.f);
            sc[rl][ox0 + 2] = fmaxf(s2, 0.f);
            sc[rl][ox0 + 3] = fmaxf(s3, 0.f);
        }
    }
    __syncthreads();

    // pool phase: 4 classes x 11 ey x 22 ex = 968 outputs
    #pragma unroll
    for (int q2 = 0; q2 < 4; ++q2) {
        int p = tid + 256 * q2;
        if (p < 968) {
            int cls = p / 242;                  // (p1,p2)
            int cell = p - cls * 242;
            int eyl = cell / 22, ex = cell - eyl * 22;
            int ey = h * 11 + eyl;
            int p1v = cls >> 1, p2v = cls & 1;
            int r0 = 2 * ey + p1v, r1 = r0 + 1;
            if (r0 > 43) r0 = 43; if (r1 > 43) r1 = 43;
            int c0 = 2 * ex + p2v, c1 = c0 + 1;
            if (c0 > 43) c0 = 43; if (c1 > 43) c1 = 43;
            int rb = h * 22;
            float v = fmaxf(fmaxf(sc[r0 - rb][c0], sc[r0 - rb][c1]),
                            fmaxf(sc[r1 - rb][c0], sc[r1 - rb][c1]));
            pool2[((unsigned)((cls3 * 4 + cls) * 32 + oc)) * P2_PLANE + ey * 22 + ex] = v;
        }
    }
}

// FC GEMM: BM=16, 578 blocks x 512 thr (8 waves = 4 nsl x 2 kh).
// A (16 crops x K'=1536 bf16) staged ONCE in LDS via coalesced contiguous-M
// loads (m = cls5*289 + c*17 + d, d fastest); main loop = ds_read_b128 (A) +
// contiguous 1KB/wave B loads from wBt + MFMA. kh-halves reduced via LDS;
// fused bias/ReLU/FC2/sigmoid/scatter.
__global__ __launch_bounds__(512, 4) void k_fc(const float* __restrict__ pool2,
                                               const unsigned short* __restrict__ wBt,
                                               const float* __restrict__ fc1_b,
                                               const float* __restrict__ fc2_w,
                                               const float* __restrict__ fc2_b,
                                               float* __restrict__ out) {
    __shared__ __align__(16) unsigned short sa[192][16][8];   // 48 KB, frag-blocked
    __shared__ __align__(16) float shH[16][132];

    int tid = threadIdx.x;
    int m0  = blockIdx.x * 16;

    // ---- Stage A: thread = (m = tid&15, ch = tid>>4); 6 contiguous 8-float runs
    {
        int m = m0 + (tid & 15);
        int ch = tid >> 4;
        int cls5 = m / 289, r = m - cls5 * 289;
        int c = r / 17, d = r - c * 17;
        const float* abase = pool2 + cls5 * (32 * P2_PLANE) + c * 22 + d + ch * P2_PLANE;
        #pragma unroll
        for (int q = 0; q < 6; ++q) {                 // mm = q
            f32x4u lo = *(const f32x4u*)(abase + q * 22);
            f32x4u hi = *(const f32x4u*)(abase + q * 22 + 4);
            u32x4 uu = { cvtpk(lo.x, lo.y), cvtpk(lo.z, lo.w),
                         cvtpk(hi.x, hi.y), cvtpk(hi.z, hi.w) };
            *(u32x4*)&sa[q * 32 + ch][tid & 15][0] = uu;   // kb = mm*32+ch
        }
    }

    int lane = tid & 63, wid = tid >> 6;
    int nsl = wid & 3, kh = wid >> 2;
    int lm = lane & 15, lg = lane >> 4;

    const unsigned short* bp0 = wBt + (((nsl * 2) * 192) * 16 + lm) * 8;
    const unsigned short* bp1 = bp0 + 192 * 16 * 8;

    f32x4 acc0 = {0.f,0.f,0.f,0.f}, acc1 = {0.f,0.f,0.f,0.f};

    __syncthreads();

    #pragma unroll 8
    for (int kl = 0; kl < 24; ++kl) {
        int kb = (kh * 24 + kl) * 4 + lg;
        bf16x8 a  = *(const bf16x8*)&sa[kb][lm][0];
        bf16x8 b0 = *(const bf16x8*)(bp0 + kb * 128);
        bf16x8 b1 = *(const bf16x8*)(bp1 + kb * 128);
        acc0 = __builtin_amdgcn_mfma_f32_16x16x32_bf16(a, b0, acc0, 0, 0, 0);
        acc1 = __builtin_amdgcn_mfma_f32_16x16x32_bf16(a, b1, acc1, 0, 0, 0);
    }

    // Reduce kh halves. D layout: row (m) = lg*4+r, col (n) = lm.
    int col = nsl * 32 + lm;
    if (kh == 0) {
        #pragma unroll
        for (int r = 0; r < 4; ++r) {
            shH[lg * 4 + r][col]      = acc0[r];
            shH[lg * 4 + r][col + 16] = acc1[r];
        }
    }
    __syncthreads();
    if (kh == 1) {
        #pragma unroll
        for (int r = 0; r < 4; ++r) {
            shH[lg * 4 + r][col]      += acc0[r];
            shH[lg * 4 + r][col + 16] += acc1[r];
        }
    }
    __syncthreads();

    // FC2: 512 thr = 16 crops x 32 parts, 4 elems each; reduce within 32 lanes.
    int crop_l = tid >> 5, part = tid & 31;
    float4 hv = *(const float4*)&shH[crop_l][part * 4];
    float4 fb = *(const float4*)&fc1_b[part * 4];
    float4 wv = *(const float4*)&fc2_w[part * 4];
    float s = fmaxf(hv.x + fb.x, 0.f) * wv.x
            + fmaxf(hv.y + fb.y, 0.f) * wv.y
            + fmaxf(hv.z + fb.z, 0.f) * wv.z
            + fmaxf(hv.w + fb.w, 0.f) * wv.w;
    s += __shfl_down(s, 16, 32);
    s += __shfl_down(s, 8, 32);
    s += __shfl_down(s, 4, 32);
    s += __shfl_down(s, 2, 32);
    s += __shfl_down(s, 1, 32);
    if (part == 0) {
        int m = m0 + crop_l;                 // < 9248 always
        int cls5 = m / 289, r2 = m - cls5 * 289;
        int c = r2 / 17, d = r2 - c * 17;
        int img = cls5 >> 4, o1 = (cls5 >> 3) & 1, o2 = (cls5 >> 2) & 1;
        int p1 = (cls5 >> 1) & 1, p2 = cls5 & 1;
        int i = 4 * c + 2 * p1 + o1;
        int j = 4 * d + 2 * p2 + o2;
        if (i <= 64 && j <= 64) {
            float q = 1.f / (1.f + expf(-(s + fc2_b[0])));
            out[img * (HIMG * HIMG) + (16 + i) * HIMG + (16 + j)] = q;
        }
    }
}

extern "C" void kernel_launch(void* const* d_in, const int* in_sizes, int n_in,
                              void* d_out, int out_size, void* d_ws, size_t ws_size,
                              hipStream_t stream) {
    const float* x     = (const float*)d_in[0];
    const float* w1    = (const float*)d_in[1];
    const float* b1    = (const float*)d_in[2];
    const float* w2    = (const float*)d_in[3];
    const float* b2    = (const float*)d_in[4];
    const float* fc1_w = (const float*)d_in[5];
    const float* fc1_b = (const float*)d_in[6];
    const float* fc2_w = (const float*)d_in[7];
    const float* fc2_b = (const float*)d_in[8];
    float* out = (float*)d_out;

    float* ws    = (float*)d_ws;
    float* pool1 = ws;                         // 270848 f32
    float* pool2 = pool1 + P1_SIZE;            // 495616 f32
    unsigned short* wBt = (unsigned short*)(pool2 + P2_SIZE);  // 196608 bf16

    k_front<<<697, 256, 0, stream>>>(x, w1, b1, pool1, fc1_w, wBt, out);
    k_convpool<<<512, 256, 0, stream>>>(pool1, w2, b2, pool2);
    k_fc<<<578, 512, 0, stream>>>(pool2, wBt, fc1_b, fc2_w, fc2_b, out);
}

// Round 10
// 40.661 us; speedup vs baseline: 1.5011x; 1.1283x over previous
//
#include <hip/hip_runtime.h>
#include <math.h>

// Problem constants
#define NB 2
#define HIMG 96
#define HO 65
#define NCROPS (NB*HO*HO)   // 8450

// pool1: [cls3=(img,o1,o2)][16ch][46][46]
#define P1_PLANE (46*46)          // 2116
#define P1_SIZE (8*16*P1_PLANE)   // 270848
// pool2: [cls5=(img,o1,o2,p1,p2)][32ch][22][22] f32
#define P2_PLANE (22*22)          // 484
#define P2_SIZE (32*32*P2_PLANE)  // 495616
// wBt: fragment-blocked NATIVE-K weights [nf 8][g 144][lm 16][8] bf16
//   k = g*8 + e  (k = ch*36 + mm*6 + nn, native order), n = nf*16 + lm
#define WBT_SIZE (8*144*16*8)     // 147456

typedef __attribute__((ext_vector_type(8))) short bf16x8;
typedef __attribute__((ext_vector_type(4))) float f32x4;
typedef __attribute__((ext_vector_type(4), aligned(4))) float f32x4u;  // 4B-aligned vec load

__device__ __forceinline__ unsigned int f2bf(float x) {
    unsigned int u = __builtin_bit_cast(unsigned int, x);
    return (u + 0x7fffu + ((u >> 16) & 1u)) >> 16;
}
__device__ __forceinline__ unsigned int cvtpk(float lo, float hi) {
    unsigned int r;
    asm("v_cvt_pk_bf16_f32 %0, %1, %2" : "=v"(r) : "v"(lo), "v"(hi));
    return r;
}

// Merged front kernel:
//   blocks [0,529)   : conv1(5x5,1->16)+ReLU+2x2 maxpool at parity -> pool1
//   blocks [529,601) : build wBt (native-K fragment-blocked bf16 fc1 weights)
//   blocks [601,673) : zero heatmap
__global__ void k_front(const float* __restrict__ x, const float* __restrict__ w1,
                        const float* __restrict__ b1, float* __restrict__ pool1,
                        const float* __restrict__ fc1_w, unsigned short* __restrict__ wBt,
                        float* __restrict__ out) {
    int b = blockIdx.x, tid = threadIdx.x;
    if (b >= 529) {
        if (b < 601) {
            int g2 = (b - 529) * 256 + tid;       // < 18432, one 16B chunk each
            int lm = g2 & 15;
            int gg = (g2 >> 4) % 144;
            int nf = g2 / 2304;
            int n  = nf * 16 + lm;
            const float* src = fc1_w + n * 1152 + gg * 8;   // 8 consecutive native k
            f32x4u s0 = *(const f32x4u*)src;
            f32x4u s1 = *(const f32x4u*)(src + 4);
            uint4 v;
            v.x = f2bf(s0.x) | (f2bf(s0.y) << 16);
            v.y = f2bf(s0.z) | (f2bf(s0.w) << 16);
            v.z = f2bf(s1.x) | (f2bf(s1.y) << 16);
            v.w = f2bf(s1.z) | (f2bf(s1.w) << 16);
            ((uint4*)wBt)[g2] = v;
        } else {
            out[(b - 601) * 256 + tid] = 0.f;
        }
        return;
    }
    int idx = b * 256 + tid;                          // < 135424
    int pg = idx % 23;
    int t  = idx / 23;
    int py = t % 46;  t /= 46;
    int ch = t % 16;  t /= 16;                        // t = cls3
    int o2 = t & 1, o1 = (t >> 1) & 1, img = t >> 2;
    const float* xim = x + img * (HIMG * HIMG);

    int rbase = 2 * py + o1;
    int cbase = 4 * pg + o2;
    float a[6][8];
    #pragma unroll
    for (int i = 0; i < 6; ++i) {
        int r = rbase + i; if (r > 95) r = 95;
        const float* rp = xim + r * 96;
        #pragma unroll
        for (int j = 0; j < 8; ++j) {
            int c = cbase + j; if (c > 95) c = 95;
            a[i][j] = rp[c];
        }
    }
    const float* wc = w1 + ch * 25;
    float w[25];
    #pragma unroll
    for (int u = 0; u < 25; ++u) w[u] = wc[u];
    float bias = b1[ch];

    float out0 = 0.f, out1 = 0.f;   // relu'd values >= 0
    #pragma unroll
    for (int dy = 0; dy < 2; ++dy)
        #pragma unroll
        for (int dx = 0; dx < 2; ++dx) {
            float s0 = bias, s1 = bias;
            #pragma unroll
            for (int ky = 0; ky < 5; ++ky)
                #pragma unroll
                for (int kx = 0; kx < 5; ++kx) {
                    float wv = w[ky * 5 + kx];
                    s0 += a[dy + ky][dx + kx] * wv;
                    s1 += a[dy + ky][2 + dx + kx] * wv;
                }
            out0 = fmaxf(out0, s0);
            out1 = fmaxf(out1, s1);
        }
    int base = ((t * 16 + ch) * 46 + py) * 46 + 2 * pg;
    float2 v; v.x = out0; v.y = out1;
    *(float2*)&pool1[base] = v;
}

// Fused conv2(3x3,16->32)+ReLU+pool2: block = (cls3, oc, row-half h).
// Computes a 23-row conv2 strip into LDS, then pools all 4 (p1,p2) classes.
__global__ __launch_bounds__(256) void k_convpool(const float* __restrict__ pool1,
                                                  const float* __restrict__ w2,
                                                  const float* __restrict__ b2,
                                                  float* __restrict__ pool2) {
    __shared__ float sc[23][45];
    int b = blockIdx.x;                     // < 512
    int h = b & 1, oc = (b >> 1) & 31, cls3 = b >> 6;
    int tid = threadIdx.x;
    const float* p1base = pool1 + cls3 * 16 * P1_PLANE;
    const float* ww = w2 + oc * 144;        // block-uniform -> scalarized
    float bias = b2[oc];

    if (tid < 253) {
        int rl = tid / 11, og = tid - rl * 11;
        int oy = h * 22 + rl;
        if (oy < 44) {
            int ox0 = og * 4;
            const float* p1 = p1base + oy * 46 + ox0;
            float s0 = bias, s1 = bias, s2 = bias, s3 = bias;
            for (int ic = 0; ic < 16; ++ic) {
                const float* pp = p1 + ic * P1_PLANE;
                const float* wk = ww + ic * 9;
                #pragma unroll
                for (int ky = 0; ky < 3; ++ky) {
                    const float* r = pp + ky * 46;
                    float w0 = wk[ky * 3], w1v = wk[ky * 3 + 1], w2v = wk[ky * 3 + 2];
                    float a0 = r[0], a1 = r[1], a2 = r[2], a3 = r[3], a4 = r[4], a5 = r[5];
                    s0 += a0 * w0 + a1 * w1v + a2 * w2v;
                    s1 += a1 * w0 + a2 * w1v + a3 * w2v;
                    s2 += a2 * w0 + a3 * w1v + a4 * w2v;
                    s3 += a3 * w0 + a4 * w1v + a5 * w2v;
                }
            }
            sc[rl][ox0]     = fmaxf(s0, 0.f);
            sc[rl][ox0 + 1] = fmaxf(s1, 0.f);
            sc[rl][ox0 + 2] = fmaxf(s2, 0.f);
            sc[rl][ox0 + 3] = fmaxf(s3, 0.f);
        }
    }
    __syncthreads();

    #pragma unroll
    for (int q2 = 0; q2 < 4; ++q2) {
        int p = tid + 256 * q2;
        if (p < 968) {
            int cls = p / 242;                  // (p1,p2)
            int cell = p - cls * 242;
            int eyl = cell / 22, ex = cell - eyl * 22;
            int ey = h * 11 + eyl;
            int p1v = cls >> 1, p2v = cls & 1;
            int r0 = 2 * ey + p1v, r1 = r0 + 1;
            if (r0 > 43) r0 = 43; if (r1 > 43) r1 = 43;
            int c0 = 2 * ex + p2v, c1 = c0 + 1;
            if (c0 > 43) c0 = 43; if (c1 > 43) c1 = 43;
            int rb = h * 22;
            float v = fmaxf(fmaxf(sc[r0 - rb][c0], sc[r0 - rb][c1]),
                            fmaxf(sc[r1 - rb][c0], sc[r1 - rb][c1]));
            pool2[((unsigned)((cls3 * 4 + cls) * 32 + oc)) * P2_PLANE + ey * 22 + ex] = v;
        }
    }
}

// FC GEMM: BM=16, native K=1152 (36 slices), 578 blocks x 512 thr
// (8 waves = 4 nsl x 2 kh). A staged once in LDS [16][1160] bf16 (36.3 KB,
// union'd with the epilogue H buffer -> 4 blocks/CU, all blocks resident).
// Main loop: ds_read_b128 (A) + two contiguous 1KB/wave B loads + 2 MFMA.
__global__ __launch_bounds__(512, 4) void k_fc(const float* __restrict__ pool2,
                                               const unsigned short* __restrict__ wBt,
                                               const float* __restrict__ fc1_b,
                                               const float* __restrict__ fc2_w,
                                               const float* __restrict__ fc2_b,
                                               float* __restrict__ out) {
    __shared__ __align__(16) union ShMem {
        unsigned short a[16][1160];   // row stride 2320 B (16B-aligned; 2-way banks)
        float h[16][132];             // epilogue overlay (8.4 KB < 36.3 KB)
    } sh;

    int tid = threadIdx.x;
    int m0  = blockIdx.x * 16;

    // ---- Stage A: thread = (m = tid&15, ch = tid>>4) packs its channel's
    // 6x6 window into native k = ch*36 + mm*6 + nn (72 B contiguous).
    {
        int m = m0 + (tid & 15);
        int ch = tid >> 4;
        int cls5 = m / 289, r = m - cls5 * 289;
        int c = r / 17, d = r - c * 17;
        const float* abase = pool2 + cls5 * (32 * P2_PLANE) + ch * P2_PLANE + c * 22 + d;
        unsigned int arr[18];
        #pragma unroll
        for (int mm = 0; mm < 6; ++mm) {
            f32x4u lo = *(const f32x4u*)(abase + mm * 22);
            f32x4u hi = *(const f32x4u*)(abase + mm * 22 + 4);
            arr[mm * 3 + 0] = cvtpk(lo.x, lo.y);
            arr[mm * 3 + 1] = cvtpk(lo.z, lo.w);
            arr[mm * 3 + 2] = cvtpk(hi.x, hi.y);
        }
        uint2* dst = (uint2*)&sh.a[tid & 15][ch * 36];
        #pragma unroll
        for (int q = 0; q < 9; ++q) {
            uint2 w; w.x = arr[2 * q]; w.y = arr[2 * q + 1];
            dst[q] = w;
        }
    }

    int lane = tid & 63, wid = tid >> 6;
    int nsl = wid & 3, kh = wid >> 2;
    int lm = lane & 15, lg = lane >> 4;

    // B: addr(shorts) = nf*18432 + ks*512 + lg*128 + lm*8; wave instr = 1KB contiguous
    const unsigned short* bp0 = wBt + (nsl * 2) * 18432 + kh * 9216 + lg * 128 + lm * 8;
    const unsigned short* bp1 = bp0 + 18432;
    const unsigned short* ap  = &sh.a[lm][kh * 576 + lg * 8];

    f32x4 acc0 = {0.f,0.f,0.f,0.f}, acc1 = {0.f,0.f,0.f,0.f};

    __syncthreads();

    #pragma unroll 6
    for (int kl = 0; kl < 18; ++kl) {
        bf16x8 a  = *(const bf16x8*)(ap + kl * 32);
        bf16x8 b0 = *(const bf16x8*)(bp0 + kl * 512);
        bf16x8 b1 = *(const bf16x8*)(bp1 + kl * 512);
        acc0 = __builtin_amdgcn_mfma_f32_16x16x32_bf16(a, b0, acc0, 0, 0, 0);
        acc1 = __builtin_amdgcn_mfma_f32_16x16x32_bf16(a, b1, acc1, 0, 0, 0);
    }

    __syncthreads();   // all sa reads complete before H overlay

    // Reduce kh halves. D layout: row (m) = lg*4+r, col (n) = lm.
    int col = nsl * 32 + lm;
    if (kh == 0) {
        #pragma unroll
        for (int r = 0; r < 4; ++r) {
            sh.h[lg * 4 + r][col]      = acc0[r];
            sh.h[lg * 4 + r][col + 16] = acc1[r];
        }
    }
    __syncthreads();
    if (kh == 1) {
        #pragma unroll
        for (int r = 0; r < 4; ++r) {
            sh.h[lg * 4 + r][col]      += acc0[r];
            sh.h[lg * 4 + r][col + 16] += acc1[r];
        }
    }
    __syncthreads();

    // FC2: 512 thr = 16 crops x 32 parts, 4 elems each; reduce within 32 lanes.
    int crop_l = tid >> 5, part = tid & 31;
    float4 hv = *(const float4*)&sh.h[crop_l][part * 4];
    float4 fb = *(const float4*)&fc1_b[part * 4];
    float4 wv = *(const float4*)&fc2_w[part * 4];
    float s = fmaxf(hv.x + fb.x, 0.f) * wv.x
            + fmaxf(hv.y + fb.y, 0.f) * wv.y
            + fmaxf(hv.z + fb.z, 0.f) * wv.z
            + fmaxf(hv.w + fb.w, 0.f) * wv.w;
    s += __shfl_down(s, 16, 32);
    s += __shfl_down(s, 8, 32);
    s += __shfl_down(s, 4, 32);
    s += __shfl_down(s, 2, 32);
    s += __shfl_down(s, 1, 32);
    if (part == 0) {
        int m = m0 + crop_l;                 // < 9248 always
        int cls5 = m / 289, r2 = m - cls5 * 289;
        int c = r2 / 17, d = r2 - c * 17;
        int img = cls5 >> 4, o1 = (cls5 >> 3) & 1, o2 = (cls5 >> 2) & 1;
        int p1 = (cls5 >> 1) & 1, p2 = cls5 & 1;
        int i = 4 * c + 2 * p1 + o1;
        int j = 4 * d + 2 * p2 + o2;
        if (i <= 64 && j <= 64) {
            float q = 1.f / (1.f + expf(-(s + fc2_b[0])));
            out[img * (HIMG * HIMG) + (16 + i) * HIMG + (16 + j)] = q;
        }
    }
}

extern "C" void kernel_launch(void* const* d_in, const int* in_sizes, int n_in,
                              void* d_out, int out_size, void* d_ws, size_t ws_size,
                              hipStream_t stream) {
    const float* x     = (const float*)d_in[0];
    const float* w1    = (const float*)d_in[1];
    const float* b1    = (const float*)d_in[2];
    const float* w2    = (const float*)d_in[3];
    const float* b2    = (const float*)d_in[4];
    const float* fc1_w = (const float*)d_in[5];
    const float* fc1_b = (const float*)d_in[6];
    const float* fc2_w = (const float*)d_in[7];
    const float* fc2_b = (const float*)d_in[8];
    float* out = (float*)d_out;

    float* ws    = (float*)d_ws;
    float* pool1 = ws;                         // 270848 f32
    float* pool2 = pool1 + P1_SIZE;            // 495616 f32
    unsigned short* wBt = (unsigned short*)(pool2 + P2_SIZE);  // 147456 bf16

    k_front<<<673, 256, 0, stream>>>(x, w1, b1, pool1, fc1_w, wBt, out);
    k_convpool<<<512, 256, 0, stream>>>(pool1, w2, b2, pool2);
    k_fc<<<578, 512, 0, stream>>>(pool2, wBt, fc1_b, fc2_w, fc2_b, out);
}

// Round 11
// 32.406 us; speedup vs baseline: 1.8835x; 1.2547x over previous
//
#include <hip/hip_runtime.h>
#include <math.h>

// Problem constants
#define NB 2
#define HIMG 96
#define HO 65
#define NCROPS (NB*HO*HO)   // 8450

// pool1: [cls3=(img,o1,o2)][16ch][46][46]
#define P1_PLANE (46*46)          // 2116
#define P1_SIZE (8*16*P1_PLANE)   // 270848
// pool2: [cls5=(img,o1,o2,p1,p2)][32ch][22][22] f32
#define P2_PLANE (22*22)          // 484
#define P2_SIZE (32*32*P2_PLANE)  // 495616
// wBt: fragment-blocked NATIVE-K weights [nf 8][g 144][lm 16][8] bf16
#define WBT_SIZE (8*144*16*8)     // 147456

typedef __attribute__((ext_vector_type(8))) short bf16x8;
typedef __attribute__((ext_vector_type(4))) float f32x4;
typedef __attribute__((ext_vector_type(4), aligned(4))) float f32x4u;  // 4B-aligned vec load

__device__ __forceinline__ unsigned int f2bf(float x) {
    unsigned int u = __builtin_bit_cast(unsigned int, x);
    return (u + 0x7fffu + ((u >> 16) & 1u)) >> 16;
}
__device__ __forceinline__ unsigned int cvtpk(float lo, float hi) {
    unsigned int r;
    asm("v_cvt_pk_bf16_f32 %0, %1, %2" : "=v"(r) : "v"(lo), "v"(hi));
    return r;
}

// Merged front kernel:
//   blocks [0,529)   : conv1(5x5,1->16)+ReLU+2x2 maxpool at parity -> pool1
//   blocks [529,601) : build wBt (native-K fragment-blocked bf16 fc1 weights)
//   blocks [601,673) : zero heatmap
__global__ void k_front(const float* __restrict__ x, const float* __restrict__ w1,
                        const float* __restrict__ b1, float* __restrict__ pool1,
                        const float* __restrict__ fc1_w, unsigned short* __restrict__ wBt,
                        float* __restrict__ out) {
    int b = blockIdx.x, tid = threadIdx.x;
    if (b >= 529) {
        if (b < 601) {
            int g2 = (b - 529) * 256 + tid;       // < 18432, one 16B chunk each
            int lm = g2 & 15;
            int gg = (g2 >> 4) % 144;
            int nf = g2 / 2304;
            int n  = nf * 16 + lm;
            const float* src = fc1_w + n * 1152 + gg * 8;   // 8 consecutive native k
            f32x4u s0 = *(const f32x4u*)src;
            f32x4u s1 = *(const f32x4u*)(src + 4);
            uint4 v;
            v.x = f2bf(s0.x) | (f2bf(s0.y) << 16);
            v.y = f2bf(s0.z) | (f2bf(s0.w) << 16);
            v.z = f2bf(s1.x) | (f2bf(s1.y) << 16);
            v.w = f2bf(s1.z) | (f2bf(s1.w) << 16);
            ((uint4*)wBt)[g2] = v;
        } else {
            out[(b - 601) * 256 + tid] = 0.f;
        }
        return;
    }
    int idx = b * 256 + tid;                          // < 135424
    int pg = idx % 23;
    int t  = idx / 23;
    int py = t % 46;  t /= 46;
    int ch = t % 16;  t /= 16;                        // t = cls3
    int o2 = t & 1, o1 = (t >> 1) & 1, img = t >> 2;
    const float* xim = x + img * (HIMG * HIMG);

    int rbase = 2 * py + o1;
    int cb = 4 * pg + o2;
    bool cshift = (cb == 89);          // only (pg==22, o2==1) overflows cols
    if (cshift) cb = 88;
    float a[6][8];
    #pragma unroll
    for (int i = 0; i < 6; ++i) {
        int r = rbase + i; if (r > 95) r = 95;        // row clamp (py=45,o1=1)
        const float* rp = xim + r * 96 + cb;
        f32x4u lo = *(const f32x4u*)rp;
        f32x4u hi = *(const f32x4u*)(rp + 4);
        a[i][0] = lo.x; a[i][1] = lo.y; a[i][2] = lo.z; a[i][3] = lo.w;
        a[i][4] = hi.x; a[i][5] = hi.y; a[i][6] = hi.z; a[i][7] = hi.w;
    }
    if (cshift) {
        // loaded cols 88..95; need cols min(89+j,95): shift left, keep last
        #pragma unroll
        for (int i = 0; i < 6; ++i)
            #pragma unroll
            for (int j = 0; j < 7; ++j) a[i][j] = a[i][j + 1];
    }
    const float* wc = w1 + ch * 25;
    float w[25];
    #pragma unroll
    for (int u = 0; u < 25; ++u) w[u] = wc[u];
    float bias = b1[ch];

    float out0 = 0.f, out1 = 0.f;   // relu'd values >= 0
    #pragma unroll
    for (int dy = 0; dy < 2; ++dy)
        #pragma unroll
        for (int dx = 0; dx < 2; ++dx) {
            float s0 = bias, s1 = bias;
            #pragma unroll
            for (int ky = 0; ky < 5; ++ky)
                #pragma unroll
                for (int kx = 0; kx < 5; ++kx) {
                    float wv = w[ky * 5 + kx];
                    s0 += a[dy + ky][dx + kx] * wv;
                    s1 += a[dy + ky][2 + dx + kx] * wv;
                }
            out0 = fmaxf(out0, s0);
            out1 = fmaxf(out1, s1);
        }
    int base = ((t * 16 + ch) * 46 + py) * 46 + 2 * pg;
    float2 v; v.x = out0; v.y = out1;
    *(float2*)&pool1[base] = v;
}

// Fused conv2(3x3,16->32)+ReLU+pool2: block = (cls3, oc, row-half h).
// Conv rows loaded as two f32x4u (8 floats) instead of 6 scalars: 96 loads/thr.
// Vector tails read <=2 floats past pool1 (into pool2 region of ws; unused).
__global__ __launch_bounds__(256) void k_convpool(const float* __restrict__ pool1,
                                                  const float* __restrict__ w2,
                                                  const float* __restrict__ b2,
                                                  float* __restrict__ pool2) {
    __shared__ float sc[23][45];
    int b = blockIdx.x;                     // < 512
    int h = b & 1, oc = (b >> 1) & 31, cls3 = b >> 6;
    int tid = threadIdx.x;
    const float* p1base = pool1 + cls3 * 16 * P1_PLANE;
    const float* ww = w2 + oc * 144;        // block-uniform -> scalarized
    float bias = b2[oc];

    if (tid < 253) {
        int rl = tid / 11, og = tid - rl * 11;
        int oy = h * 22 + rl;
        if (oy < 44) {
            int ox0 = og * 4;
            const float* p1 = p1base + oy * 46 + ox0;
            float s0 = bias, s1 = bias, s2 = bias, s3 = bias;
            for (int ic = 0; ic < 16; ++ic) {
                const float* pp = p1 + ic * P1_PLANE;
                const float* wk = ww + ic * 9;
                #pragma unroll
                for (int ky = 0; ky < 3; ++ky) {
                    const float* r = pp + ky * 46;
                    f32x4u lo = *(const f32x4u*)r;
                    f32x4u hi = *(const f32x4u*)(r + 4);
                    float w0 = wk[ky * 3], w1v = wk[ky * 3 + 1], w2v = wk[ky * 3 + 2];
                    s0 += lo.x * w0 + lo.y * w1v + lo.z * w2v;
                    s1 += lo.y * w0 + lo.z * w1v + lo.w * w2v;
                    s2 += lo.z * w0 + lo.w * w1v + hi.x * w2v;
                    s3 += lo.w * w0 + hi.x * w1v + hi.y * w2v;
                }
            }
            sc[rl][ox0]     = fmaxf(s0, 0.f);
            sc[rl][ox0 + 1] = fmaxf(s1, 0.f);
            sc[rl][ox0 + 2] = fmaxf(s2, 0.f);
            sc[rl][ox0 + 3] = fmaxf(s3, 0.f);
        }
    }
    __syncthreads();

    #pragma unroll
    for (int q2 = 0; q2 < 4; ++q2) {
        int p = tid + 256 * q2;
        if (p < 968) {
            int cls = p / 242;                  // (p1,p2)
            int cell = p - cls * 242;
            int eyl = cell / 22, ex = cell - eyl * 22;
            int ey = h * 11 + eyl;
            int p1v = cls >> 1, p2v = cls & 1;
            int r0 = 2 * ey + p1v, r1 = r0 + 1;
            if (r0 > 43) r0 = 43; if (r1 > 43) r1 = 43;
            int c0 = 2 * ex + p2v, c1 = c0 + 1;
            if (c0 > 43) c0 = 43; if (c1 > 43) c1 = 43;
            int rb = h * 22;
            float v = fmaxf(fmaxf(sc[r0 - rb][c0], sc[r0 - rb][c1]),
                            fmaxf(sc[r1 - rb][c0], sc[r1 - rb][c1]));
            pool2[((unsigned)((cls3 * 4 + cls) * 32 + oc)) * P2_PLANE + ey * 22 + ex] = v;
        }
    }
}

// FC GEMM: BM=16, native K=1152 (36 slices), 578 blocks x 512 thr
// (8 waves = 4 nsl x 2 kh). A staged once in LDS [16][1160] bf16 (36.3 KB,
// union'd with the epilogue H buffer -> 4 blocks/CU, all blocks resident).
__global__ __launch_bounds__(512, 4) void k_fc(const float* __restrict__ pool2,
                                               const unsigned short* __restrict__ wBt,
                                               const float* __restrict__ fc1_b,
                                               const float* __restrict__ fc2_w,
                                               const float* __restrict__ fc2_b,
                                               float* __restrict__ out) {
    __shared__ __align__(16) union ShMem {
        unsigned short a[16][1160];   // row stride 2320 B (16B-aligned; 2-way banks)
        float h[16][132];             // epilogue overlay (8.4 KB < 36.3 KB)
    } sh;

    int tid = threadIdx.x;
    int m0  = blockIdx.x * 16;

    // ---- Stage A: thread = (m = tid&15, ch = tid>>4) packs its channel's
    // 6x6 window into native k = ch*36 + mm*6 + nn (72 B contiguous).
    {
        int m = m0 + (tid & 15);
        int ch = tid >> 4;
        int cls5 = m / 289, r = m - cls5 * 289;
        int c = r / 17, d = r - c * 17;
        const float* abase = pool2 + cls5 * (32 * P2_PLANE) + ch * P2_PLANE + c * 22 + d;
        unsigned int arr[18];
        #pragma unroll
        for (int mm = 0; mm < 6; ++mm) {
            f32x4u lo = *(const f32x4u*)(abase + mm * 22);
            f32x4u hi = *(const f32x4u*)(abase + mm * 22 + 4);
            arr[mm * 3 + 0] = cvtpk(lo.x, lo.y);
            arr[mm * 3 + 1] = cvtpk(lo.z, lo.w);
            arr[mm * 3 + 2] = cvtpk(hi.x, hi.y);
        }
        uint2* dst = (uint2*)&sh.a[tid & 15][ch * 36];
        #pragma unroll
        for (int q = 0; q < 9; ++q) {
            uint2 w; w.x = arr[2 * q]; w.y = arr[2 * q + 1];
            dst[q] = w;
        }
    }

    int lane = tid & 63, wid = tid >> 6;
    int nsl = wid & 3, kh = wid >> 2;
    int lm = lane & 15, lg = lane >> 4;

    const unsigned short* bp0 = wBt + (nsl * 2) * 18432 + kh * 9216 + lg * 128 + lm * 8;
    const unsigned short* bp1 = bp0 + 18432;
    const unsigned short* ap  = &sh.a[lm][kh * 576 + lg * 8];

    f32x4 acc0 = {0.f,0.f,0.f,0.f}, acc1 = {0.f,0.f,0.f,0.f};

    __syncthreads();

    #pragma unroll 6
    for (int kl = 0; kl < 18; ++kl) {
        bf16x8 a  = *(const bf16x8*)(ap + kl * 32);
        bf16x8 b0 = *(const bf16x8*)(bp0 + kl * 512);
        bf16x8 b1 = *(const bf16x8*)(bp1 + kl * 512);
        acc0 = __builtin_amdgcn_mfma_f32_16x16x32_bf16(a, b0, acc0, 0, 0, 0);
        acc1 = __builtin_amdgcn_mfma_f32_16x16x32_bf16(a, b1, acc1, 0, 0, 0);
    }

    __syncthreads();   // all sa reads complete before H overlay

    int col = nsl * 32 + lm;
    if (kh == 0) {
        #pragma unroll
        for (int r = 0; r < 4; ++r) {
            sh.h[lg * 4 + r][col]      = acc0[r];
            sh.h[lg * 4 + r][col + 16] = acc1[r];
        }
    }
    __syncthreads();
    if (kh == 1) {
        #pragma unroll
        for (int r = 0; r < 4; ++r) {
            sh.h[lg * 4 + r][col]      += acc0[r];
            sh.h[lg * 4 + r][col + 16] += acc1[r];
        }
    }
    __syncthreads();

    // FC2: 512 thr = 16 crops x 32 parts, 4 elems each; reduce within 32 lanes.
    int crop_l = tid >> 5, part = tid & 31;
    float4 hv = *(const float4*)&sh.h[crop_l][part * 4];
    float4 fb = *(const float4*)&fc1_b[part * 4];
    float4 wv = *(const float4*)&fc2_w[part * 4];
    float s = fmaxf(hv.x + fb.x, 0.f) * wv.x
            + fmaxf(hv.y + fb.y, 0.f) * wv.y
            + fmaxf(hv.z + fb.z, 0.f) * wv.z
            + fmaxf(hv.w + fb.w, 0.f) * wv.w;
    s += __shfl_down(s, 16, 32);
    s += __shfl_down(s, 8, 32);
    s += __shfl_down(s, 4, 32);
    s += __shfl_down(s, 2, 32);
    s += __shfl_down(s, 1, 32);
    if (part == 0) {
        int m = m0 + crop_l;                 // < 9248 always
        int cls5 = m / 289, r2 = m - cls5 * 289;
        int c = r2 / 17, d = r2 - c * 17;
        int img = cls5 >> 4, o1 = (cls5 >> 3) & 1, o2 = (cls5 >> 2) & 1;
        int p1 = (cls5 >> 1) & 1, p2 = cls5 & 1;
        int i = 4 * c + 2 * p1 + o1;
        int j = 4 * d + 2 * p2 + o2;
        if (i <= 64 && j <= 64) {
            float q = 1.f / (1.f + expf(-(s + fc2_b[0])));
            out[img * (HIMG * HIMG) + (16 + i) * HIMG + (16 + j)] = q;
        }
    }
}

extern "C" void kernel_launch(void* const* d_in, const int* in_sizes, int n_in,
                              void* d_out, int out_size, void* d_ws, size_t ws_size,
                              hipStream_t stream) {
    const float* x     = (const float*)d_in[0];
    const float* w1    = (const float*)d_in[1];
    const float* b1    = (const float*)d_in[2];
    const float* w2    = (const float*)d_in[3];
    const float* b2    = (const float*)d_in[4];
    const float* fc1_w = (const float*)d_in[5];
    const float* fc1_b = (const float*)d_in[6];
    const float* fc2_w = (const float*)d_in[7];
    const float* fc2_b = (const float*)d_in[8];
    float* out = (float*)d_out;

    float* ws    = (float*)d_ws;
    float* pool1 = ws;                         // 270848 f32
    float* pool2 = pool1 + P1_SIZE;            // 495616 f32
    unsigned short* wBt = (unsigned short*)(pool2 + P2_SIZE);  // 147456 bf16

    k_front<<<673, 256, 0, stream>>>(x, w1, b1, pool1, fc1_w, wBt, out);
    k_convpool<<<512, 256, 0, stream>>>(pool1, w2, b2, pool2);
    k_fc<<<578, 512, 0, stream>>>(pool2, wBt, fc1_b, fc2_w, fc2_b, out);
}